// Round 24
// baseline (118.492 us; speedup 1.0000x reference)
//
#include <hip/hip_runtime.h>

// VQ quantize: z [16,256,64,64] f32, weight [1024,256] f32.
// Outputs (f32, concat): quantized, straight_through (== quantized numerically), indices.
//
// prep_w: w -> fp16 (x1024, exact pow2) tiled [o][c][8]; wn = np-replicated ||w||^2.
// argmin_fused v3: 128 rows x 1024 codes, 512 thr / 8 waves. A built once/block from
//   fp32 z (f16 swizzled LDS, 64KB). B fragments loaded DIRECTLY to registers from
//   w16 (L1/L2-resident; 4 coalesced 16B loads/wave/step) -> ZERO barriers in the
//   main loop (the only __syncthreads is after A-build); compiler pipelines loads
//   across steps/cb freely. Numerics bit-identical to r19-r23.
// tail (frozen, r23): ws_size>=14MB -> scratch in d_ws, fused finrescue+gather;
//   else r22 fallback.

#define NROWS 65536
#define DDIM 256
#define KCODES 1024
#define TAU 2e-4f
#define WWIN 2e-4f

typedef unsigned long long u64;
typedef _Float16 f16x8 __attribute__((ext_vector_type(8)));
typedef float f32x4 __attribute__((ext_vector_type(4)));

// numpy pairwise fp32 sum of 256 fl(x_i^2) (validated r3..r23)
template <typename F>
__device__ __forceinline__ float np_pairwise256_sq(F get) {
    float half[2];
#pragma unroll
    for (int h = 0; h < 2; ++h) {
        float r[8];
#pragma unroll
        for (int j = 0; j < 8; ++j) { float v = get(h * 128 + j); r[j] = __fmul_rn(v, v); }
        for (int i = 8; i < 128; i += 8)
#pragma unroll
            for (int j = 0; j < 8; ++j) {
                float v = get(h * 128 + i + j);
                r[j] = __fadd_rn(r[j], __fmul_rn(v, v));
            }
        half[h] = __fadd_rn(__fadd_rn(__fadd_rn(r[0], r[1]), __fadd_rn(r[2], r[3])),
                            __fadd_rn(__fadd_rn(r[4], r[5]), __fadd_rn(r[6], r[7])));
    }
    return __fadd_rn(half[0], half[1]);
}

// ---------------- prep: w16 = fl16(1024*w) tiled [o][c][8]; wn = np ||w||^2 --------
__global__ void prep_w_k(const float* __restrict__ w, f16x8* __restrict__ w16,
                         float* __restrict__ wn) {
    int bid = blockIdx.x;
    if (bid < 128) {
        int idx = bid * 256 + threadIdx.x;
        int o = idx >> 10, c = idx & 1023;
        const float* wp = w + (size_t)c * DDIM + o * 8;
        f16x8 hv;
#pragma unroll
        for (int j = 0; j < 8; ++j) hv[j] = (_Float16)(wp[j] * 1024.0f);  // pow2: exact
        w16[(size_t)o * 1024 + c] = hv;
    } else {
        int k = (bid - 128) * 256 + threadIdx.x;
        const float* wp = w + (size_t)k * DDIM;
        wn[k] = np_pairwise256_sq([&](int i) { return wp[i]; });
    }
}

#define DPP_MIN(CTRL) {                                                                 \
    float ov = __int_as_float(__builtin_amdgcn_mov_dpp(__float_as_int(bv), CTRL, 0xf, 0xf, false)); \
    bv = fminf(bv, ov); }

__device__ __forceinline__ int aswz(int row) {
    return (row * 16) ^ (((row >> 2) & 7) << 4);
}

// ---------------- argmin v3: A-LDS + B-direct-to-register, barrier-free loop -------
__launch_bounds__(512, 2)
__global__ void argmin_fused_k(const float* __restrict__ z, const f16x8* __restrict__ w16,
                               const float* __restrict__ wn,
                               float* __restrict__ btv, u64* __restrict__ bmk) {
    __shared__ char lA[65536];                  // A only (B is register-direct)
    const int t = threadIdx.x;
    const int lane = t & 63;
    const int l15 = lane & 15, l4 = lane >> 4;
    const int wid = t >> 6;                     // 0..7
    const int wm = wid >> 1;                    // row-quarter (32 rows)
    const int wn_ = wid & 1;                    // entry half (64 codes)
    const int p = blockIdx.x;
    const int n0 = (((p & 7) << 6) | (p >> 3)) << 7;   // XCD-chunked bijective
    const float* zb = z + (size_t)(n0 >> 12) * 1048576 + (n0 & 4095);

    {   // A-build: fp32 z -> f16, in-register 4x8 transpose, swizzled ds_write
        int oc = t >> 5;                        // 0..15
        int rq = t & 31;                        // rows 4rq..4rq+3
#pragma unroll
        for (int p2 = 0; p2 < 2; ++p2) {
            int o = p2 * 16 + oc;               // 0..31
            float4 L[8];
#pragma unroll
            for (int j = 0; j < 8; ++j)
                L[j] = *reinterpret_cast<const float4*>(zb + (size_t)(o * 8 + j) * 4096 + rq * 4);
#pragma unroll
            for (int k = 0; k < 4; ++k) {
                f16x8 rec;
#pragma unroll
                for (int j = 0; j < 8; ++j) {
                    const float* lj = reinterpret_cast<const float*>(&L[j]);
                    rec[j] = (_Float16)lj[k];   // RNE, same as all validated rounds
                }
                *reinterpret_cast<f16x8*>(lA + o * 2048 + aswz(rq * 4 + k)) = rec;
            }
        }
    }
    __syncthreads();                            // the ONLY block-wide barrier

#pragma unroll 1
    for (int cb = 0; cb < 8; ++cb) {
        f32x4 acc[2][4];
#pragma unroll
        for (int mt = 0; mt < 2; ++mt)
#pragma unroll
            for (int nt = 0; nt < 4; ++nt) acc[mt][nt] = f32x4{0.f, 0.f, 0.f, 0.f};

        const f16x8* bbase = w16 + (size_t)l4 * 1024 + cb * 128 + wn_ * 64 + l15;
#pragma unroll
        for (int s = 0; s < 8; ++s) {
            f16x8 a[2], b[4];
#pragma unroll
            for (int nt = 0; nt < 4; ++nt)      // 4 coalesced 16B global loads (L1/L2)
                b[nt] = bbase[(size_t)s * 4096 + nt * 16];
            const char* pa = lA + (s * 4 + l4) * 2048;
#pragma unroll
            for (int mt = 0; mt < 2; ++mt)
                a[mt] = *reinterpret_cast<const f16x8*>(pa + aswz(wm * 32 + mt * 16 + l15));
#pragma unroll
            for (int mt = 0; mt < 2; ++mt)
#pragma unroll
                for (int nt = 0; nt < 4; ++nt)
                    acc[mt][nt] = __builtin_amdgcn_mfma_f32_16x16x32_f16(a[mt], b[nt], acc[mt][nt], 0, 0, 0);
        }

        const int c0 = cb << 7;
        float wnv[4];
#pragma unroll
        for (int nt = 0; nt < 4; ++nt) wnv[nt] = wn[c0 + wn_ * 64 + nt * 16 + l15];
        const int ebase = ((cb << 1) | wn_) << 16;
#pragma unroll
        for (int mt = 0; mt < 2; ++mt) {
#pragma unroll
            for (int r = 0; r < 4; ++r) {
                // C/D layout: col = lane&15, row = (lane>>4)*4 + r
                float s0 = fmaf(-0.001953125f, acc[mt][0][r], wnv[0]);   // -2^-9 (w x1024)
                float s1 = fmaf(-0.001953125f, acc[mt][1][r], wnv[1]);
                float s2 = fmaf(-0.001953125f, acc[mt][2][r], wnv[2]);
                float s3 = fmaf(-0.001953125f, acc[mt][3][r], wnv[3]);
                float bv = fminf(fminf(s0, s1), fminf(s2, s3));
                DPP_MIN(0xB1)
                DPP_MIN(0x4E)
                DPP_MIN(0x141)
                DPP_MIN(0x140)
                float thr = bv + WWIN;
                u64 b0 = __ballot(s0 < thr), b1 = __ballot(s1 < thr);
                u64 b2 = __ballot(s2 < thr), b3 = __ballot(s3 < thr);
                int sh = 16 * l4;
                u64 msk = ((b0 >> sh) & 0xFFFFull)
                        | (((b1 >> sh) & 0xFFFFull) << 16)
                        | (((b2 >> sh) & 0xFFFFull) << 32)
                        | (((b3 >> sh) & 0xFFFFull) << 48);
                if (l15 == 0) {
                    int row = wm * 32 + mt * 16 + l4 * 4 + r;
                    btv[ebase + n0 + row] = bv;
                    bmk[ebase + n0 + row] = msk;
                }
            }
        }
    }
}

// ============ tail: finrescue core shared by fused / legacy variants (frozen) ======
template <bool FUSE_GATHER>
__device__ __forceinline__ void finrescue_body(
        const float* __restrict__ z, const float* __restrict__ w,
        const float* __restrict__ s2, const float* __restrict__ btv,
        const u64* __restrict__ bmk, float* __restrict__ idxf_out,
        float* __restrict__ out0, float* __restrict__ out1,
        float (*zsh)[16][260], int (*codes)[16]) {
    const int t = threadIdx.x;
    const int lane = t & 63;
    const int wid = t >> 6;
    const int p = blockIdx.x;
    const int grp = (((p & 7) << 7) | (p >> 3)) * 4 + wid;
    const int n0 = grp * 16;
    const int r = lane >> 2;
    const int eq = lane & 3;
    const int n = n0 + r;

    float v0 = btv[((eq * 4 + 0) << 16) + n];
    float v1 = btv[((eq * 4 + 1) << 16) + n];
    float v2 = btv[((eq * 4 + 2) << 16) + n];
    float v3 = btv[((eq * 4 + 3) << 16) + n];
    float bv = 3.4e38f, b2 = 3.4e38f;
    int be = 0;
    {
        if (v0 < bv) { b2 = bv; bv = v0; be = eq * 4 + 0; } else b2 = fminf(b2, v0);
        if (v1 < bv) { b2 = bv; bv = v1; be = eq * 4 + 1; } else b2 = fminf(b2, v1);
        if (v2 < bv) { b2 = bv; bv = v2; be = eq * 4 + 2; } else b2 = fminf(b2, v2);
        if (v3 < bv) { b2 = bv; bv = v3; be = eq * 4 + 3; } else b2 = fminf(b2, v3);
    }
#pragma unroll
    for (int m = 1; m < 4; m <<= 1) {
        float ov = __shfl_xor(bv, m), o2 = __shfl_xor(b2, m);
        int oe = __shfl_xor(be, m);
        if (ov < bv || (ov == bv && oe < be)) { b2 = fminf(bv, o2); bv = ov; be = oe; }
        else b2 = fminf(b2, ov);
    }
    u64 wmask = bmk[((u64)be << 16) + n];
    int bi = be * 64 + (int)(__ffsll((long long)wmask) - 1);
    bool flag = (__popcll(wmask) > 1) || (b2 - bv < TAU);
    if (eq == 0) {
        idxf_out[n] = (float)bi;
        if (FUSE_GATHER) codes[wid][r] = bi;
    }

    u64 bal0 = __ballot(v0 <= bv + TAU);
    u64 bal1 = __ballot(v1 <= bv + TAU);
    u64 bal2 = __ballot(v2 <= bv + TAU);
    u64 bal3 = __ballot(v3 <= bv + TAU);

    u64 fb = __ballot(flag);
    if ((fb & 0x1111111111111111ull) != 0) {
        const float* zb = z + (size_t)(n0 >> 12) * 1048576 + (n0 & 4095);
#pragma unroll
        for (int it = 0; it < 16; ++it) {
            int d = it * 16 + (lane >> 2);
            float4 v = *reinterpret_cast<const float4*>(zb + (size_t)d * 4096 + (lane & 3) * 4);
            zsh[wid][(lane & 3) * 4 + 0][d] = v.x;
            zsh[wid][(lane & 3) * 4 + 1][d] = v.y;
            zsh[wid][(lane & 3) * 4 + 2][d] = v.z;
            zsh[wid][(lane & 3) * 4 + 3][d] = v.w;
        }
        asm volatile("s_waitcnt lgkmcnt(0)" ::: "memory");
        __builtin_amdgcn_sched_barrier(0);

#pragma unroll 1
        for (int r2 = 0; r2 < 16; ++r2) {
            if (!((fb >> (r2 * 4)) & 1)) continue;
            int nn = n0 + r2;
            int hh = (lane >> 3) & 1, jj = lane & 7;
            float w0 = zsh[wid][r2][hh * 128 + jj];
            float accj = __fmul_rn(w0, w0);
#pragma unroll
            for (int i = 1; i < 16; ++i) {
                float w2 = zsh[wid][r2][hh * 128 + i * 8 + jj];
                accj = __fadd_rn(accj, __fmul_rn(w2, w2));
            }
            float a1 = __fadd_rn(accj, __shfl_xor(accj, 1));
            float a2 = __fadd_rn(a1, __shfl_xor(a1, 2));
            float a4 = __fadd_rn(a2, __shfl_xor(a2, 4));
            float s1 = __fadd_rn(a4, __shfl_xor(a4, 8));

            float4 zr4 = *reinterpret_cast<const float4*>(&zsh[wid][r2][lane * 4]);
            float bv2 = 3.4e38f;
            int   bi2 = 0;
#pragma unroll
            for (int e = 0; e < 16; ++e) {
                u64 bal = (e & 3) == 0 ? bal0 : (e & 3) == 1 ? bal1 : (e & 3) == 2 ? bal2 : bal3;
                if ((bal >> (r2 * 4 + (e >> 2))) & 1) {
                    u64 m = bmk[((u64)e << 16) + nn];
                    while (m) {
                        int k = __ffsll((long long)m) - 1;
                        m &= m - 1;
                        int c = e * 64 + k;
                        const float* wp = w + (size_t)c * DDIM + lane * 4;
                        double md = 0.0;
                        md = fma((double)zr4.x, (double)wp[0], md);
                        md = fma((double)zr4.y, (double)wp[1], md);
                        md = fma((double)zr4.z, (double)wp[2], md);
                        md = fma((double)zr4.w, (double)wp[3], md);
#pragma unroll
                        for (int mm = 1; mm < 64; mm <<= 1) md += __shfl_xor(md, mm);
                        float dq = __fadd_rn((float)((double)s1 - 2.0 * md), s2[c]);
                        if (dq < bv2) { bv2 = dq; bi2 = c; }
                    }
                }
            }
            if (lane == 0) {
                idxf_out[nn] = (float)bi2;
                if (FUSE_GATHER) codes[wid][r2] = bi2;
            }
        }
    }

    if (FUSE_GATHER) {
        asm volatile("s_waitcnt lgkmcnt(0)" ::: "memory");
        __builtin_amdgcn_sched_barrier(0);
        int nr = lane & 15, c4 = lane >> 4;
        int code = codes[wid][nr];
        int nn = n0 + nr;
        size_t base = (size_t)(nn >> 12) * 1048576 + (nn & 4095);
#pragma unroll 4
        for (int p2 = 0; p2 < 16; ++p2) {
            int c = p2 * 16 + c4 * 4;
            float4 v = *reinterpret_cast<const float4*>(w + (size_t)code * DDIM + c);
            size_t o = base + (size_t)c * 4096;
            out0[o]         = v.x;
            out0[o + 4096]  = v.y;
            out0[o + 8192]  = v.z;
            out0[o + 12288] = v.w;
            out1[o]         = v.x;
            out1[o + 4096]  = v.y;
            out1[o + 8192]  = v.z;
            out1[o + 12288] = v.w;
        }
    }
}

__launch_bounds__(256, 2)
__global__ void finrescue_gather_k(const float* __restrict__ z, const float* __restrict__ w,
                                   const float* __restrict__ s2, const float* __restrict__ btv,
                                   const u64* __restrict__ bmk, float* __restrict__ idxf_out,
                                   float* __restrict__ out0, float* __restrict__ out1) {
    __shared__ float zsh[4][16][260];
    __shared__ int codes[4][16];
    finrescue_body<true>(z, w, s2, btv, bmk, idxf_out, out0, out1, zsh, codes);
}

__launch_bounds__(256, 2)
__global__ void finrescue_k(const float* __restrict__ z, const float* __restrict__ w,
                            const float* __restrict__ s2, const float* __restrict__ btv,
                            const u64* __restrict__ bmk, float* __restrict__ idxf_out) {
    __shared__ float zsh[4][16][260];
    finrescue_body<false>(z, w, s2, btv, bmk, idxf_out, nullptr, nullptr, zsh, nullptr);
}

// ---------------- legacy gather (fallback path) ----------------
__global__ void gather_k(const float* __restrict__ idxf, const float* __restrict__ w,
                         float* __restrict__ out0, float* __restrict__ out1) {
    int tid = blockIdx.x * 256 + threadIdx.x;
    int n   = tid & 65535;
    int c4  = tid >> 16;
    int code = (int)idxf[n];
    float4 v = *reinterpret_cast<const float4*>(w + (size_t)code * DDIM + c4 * 4);
    size_t off = (size_t)(n >> 12) * 1048576 + (size_t)c4 * 4 * 4096 + (n & 4095);
    out0[off]         = v.x;
    out0[off + 4096]  = v.y;
    out0[off + 8192]  = v.z;
    out0[off + 12288] = v.w;
    out1[off]         = v.x;
    out1[off + 4096]  = v.y;
    out1[off + 8192]  = v.z;
    out1[off + 12288] = v.w;
}

extern "C" void kernel_launch(void* const* d_in, const int* in_sizes, int n_in,
                              void* d_out, int out_size, void* d_ws, size_t ws_size,
                              hipStream_t stream) {
    const float* z = (const float*)d_in[0];
    const float* w = (const float*)d_in[1];
    float* out    = (float*)d_out;
    float* out0   = out;
    float* out1   = out + 16777216;
    float* outidx = out + 33554432;

    if (ws_size >= (size_t)14 * 1024 * 1024) {
        char* sb = (char*)d_ws;
        f16x8* w16 = (f16x8*)sb;                            // 512KB
        float* wn  = (float*)(sb + 1048576);                // 4KB
        float* btv = (float*)(sb + 2097152);                // 4MB  [16][65536]
        u64*   bmk = (u64*)(sb + 6291456);                  // 8MB  [16][65536]

        prep_w_k<<<132, 256, 0, stream>>>(w, w16, wn);
        argmin_fused_k<<<NROWS / 128, 512, 0, stream>>>(z, w16, wn, btv, bmk);
        finrescue_gather_k<<<NROWS / 64, 256, 0, stream>>>(z, w, wn, btv, bmk,
                                                           outidx, out0, out1);
    } else {
        char* s1b = (char*)out1;
        f16x8* w16 = (f16x8*)s1b;                           // 512KB
        float* wn  = (float*)(s1b + 1048576);               // 4KB
        float* btv = (float*)(s1b + 2097152);               // 4MB
        u64*   bmk = (u64*)(s1b + 10485760);                // 8MB

        prep_w_k<<<132, 256, 0, stream>>>(w, w16, wn);
        argmin_fused_k<<<NROWS / 128, 512, 0, stream>>>(z, w16, wn, btv, bmk);
        finrescue_k<<<NROWS / 64, 256, 0, stream>>>(z, w, wn, btv, bmk, outidx);
        gather_k<<<NROWS * 64 / 256, 256, 0, stream>>>(outidx, w, out0, out1);
    }
}

// Round 25
// 99.471 us; speedup vs baseline: 1.1912x; 1.1912x over previous
//
#include <hip/hip_runtime.h>

// VQ quantize: z [16,256,64,64] f32, weight [1024,256] f32.
// Outputs (f32, concat): quantized, straight_through (== quantized numerically), indices.
//
// r23-exact configuration (best validated: 99.6us). r24's B-direct-to-register
// experiment REGRESSED (85us argmin, latency-bound at VGPR=68: no LDS pipeline to
// carry loads across steps) -- reverted.
//
// prep_w: w -> fp16 (x1024, exact pow2) tiled [o][c][8]; wn = np-replicated ||w||^2.
// argmin_fused: 128 rows x 1024 codes, 512 thr / 8 waves, A built once/block from
//   fp32 z (f16 swizzled LDS), B gld16 counted-vmcnt double-buffer pipeline.
// tail: ws_size>=14MB -> scratch in d_ws, fused finrescue+gather; else r22 fallback.

#define NROWS 65536
#define DDIM 256
#define KCODES 1024
#define TAU 2e-4f
#define WWIN 2e-4f

typedef unsigned long long u64;
typedef _Float16 f16x8 __attribute__((ext_vector_type(8)));
typedef float f32x4 __attribute__((ext_vector_type(4)));

__device__ __forceinline__ void gld16(const void* g, void* l) {
    __builtin_amdgcn_global_load_lds((const __attribute__((address_space(1))) void*)g,
                                     (__attribute__((address_space(3))) void*)l, 16, 0, 0);
}

// numpy pairwise fp32 sum of 256 fl(x_i^2) (validated r3..r23)
template <typename F>
__device__ __forceinline__ float np_pairwise256_sq(F get) {
    float half[2];
#pragma unroll
    for (int h = 0; h < 2; ++h) {
        float r[8];
#pragma unroll
        for (int j = 0; j < 8; ++j) { float v = get(h * 128 + j); r[j] = __fmul_rn(v, v); }
        for (int i = 8; i < 128; i += 8)
#pragma unroll
            for (int j = 0; j < 8; ++j) {
                float v = get(h * 128 + i + j);
                r[j] = __fadd_rn(r[j], __fmul_rn(v, v));
            }
        half[h] = __fadd_rn(__fadd_rn(__fadd_rn(r[0], r[1]), __fadd_rn(r[2], r[3])),
                            __fadd_rn(__fadd_rn(r[4], r[5]), __fadd_rn(r[6], r[7])));
    }
    return __fadd_rn(half[0], half[1]);
}

// ---------------- prep: w16 = fl16(1024*w) tiled [o][c][8]; wn = np ||w||^2 --------
__global__ void prep_w_k(const float* __restrict__ w, f16x8* __restrict__ w16,
                         float* __restrict__ wn) {
    int bid = blockIdx.x;
    if (bid < 128) {
        int idx = bid * 256 + threadIdx.x;
        int o = idx >> 10, c = idx & 1023;
        const float* wp = w + (size_t)c * DDIM + o * 8;
        f16x8 hv;
#pragma unroll
        for (int j = 0; j < 8; ++j) hv[j] = (_Float16)(wp[j] * 1024.0f);  // pow2: exact
        w16[(size_t)o * 1024 + c] = hv;
    } else {
        int k = (bid - 128) * 256 + threadIdx.x;
        const float* wp = w + (size_t)k * DDIM;
        wn[k] = np_pairwise256_sq([&](int i) { return wp[i]; });
    }
}

#define DPP_MIN(CTRL) {                                                                 \
    float ov = __int_as_float(__builtin_amdgcn_mov_dpp(__float_as_int(bv), CTRL, 0xf, 0xf, false)); \
    bv = fminf(bv, ov); }

__device__ __forceinline__ int aswz(int row) {
    return (row * 16) ^ (((row >> 2) & 7) << 4);
}

// ---------------- fused conversion + fp16-MFMA distance; 8 waves (r22/r23) ---------
__launch_bounds__(512, 2)
__global__ void argmin_fused_k(const float* __restrict__ z, const f16x8* __restrict__ w16,
                               const float* __restrict__ wn,
                               float* __restrict__ btv, u64* __restrict__ bmk) {
    __shared__ char arena[81920];               // A 64KB | B 2x8KB
    char* lA = arena;
    char* lB = arena + 65536;
    const int t = threadIdx.x;
    const int lane = t & 63;
    const int l15 = lane & 15, l4 = lane >> 4;
    const int wid = t >> 6;                     // 0..7
    const int wm = wid >> 1;                    // row-quarter (32 rows)
    const int wn_ = wid & 1;                    // entry half (64 codes)
    const int p = blockIdx.x;
    const int n0 = (((p & 7) << 6) | (p >> 3)) << 7;   // XCD-chunked bijective
    const float* zb = z + (size_t)(n0 >> 12) * 1048576 + (n0 & 4095);

    auto STAGE_B = [&](int cb, int s, int buf) {
        int o = s * 4 + (wid >> 1);
        int half = wid & 1;
        gld16(w16 + (size_t)(o * 1024 + cb * 128 + half * 64 + lane),
              lB + buf * 8192 + wid * 1024);
    };
    STAGE_B(0, 0, 0);                           // hides under A-build

    {   // A-build: fp32 z -> f16, in-register 4x8 transpose, swizzled ds_write
        int oc = t >> 5;
        int rq = t & 31;
#pragma unroll
        for (int p2 = 0; p2 < 2; ++p2) {
            int o = p2 * 16 + oc;
            float4 L[8];
#pragma unroll
            for (int j = 0; j < 8; ++j)
                L[j] = *reinterpret_cast<const float4*>(zb + (size_t)(o * 8 + j) * 4096 + rq * 4);
#pragma unroll
            for (int k = 0; k < 4; ++k) {
                f16x8 rec;
#pragma unroll
                for (int j = 0; j < 8; ++j) {
                    const float* lj = reinterpret_cast<const float*>(&L[j]);
                    rec[j] = (_Float16)lj[k];
                }
                *reinterpret_cast<f16x8*>(lA + o * 2048 + aswz(rq * 4 + k)) = rec;
            }
        }
    }
    __syncthreads();

    auto COMPUTE = [&](int s, int buf, f32x4 (&acc)[2][4]) {
        f16x8 a[2], b[4];
        const char* pb = lB + buf * 8192 + l4 * 2048 + (wn_ * 64 + l15) * 16;
#pragma unroll
        for (int nt = 0; nt < 4; ++nt) b[nt] = *reinterpret_cast<const f16x8*>(pb + nt * 256);
        const char* pa = lA + (s * 4 + l4) * 2048;
#pragma unroll
        for (int mt = 0; mt < 2; ++mt)
            a[mt] = *reinterpret_cast<const f16x8*>(pa + aswz(wm * 32 + mt * 16 + l15));
#pragma unroll
        for (int mt = 0; mt < 2; ++mt)
#pragma unroll
            for (int nt = 0; nt < 4; ++nt)
                acc[mt][nt] = __builtin_amdgcn_mfma_f32_16x16x32_f16(a[mt], b[nt], acc[mt][nt], 0, 0, 0);
    };

#pragma unroll 1
    for (int cb = 0; cb < 8; ++cb) {
        f32x4 acc[2][4];
#pragma unroll
        for (int mt = 0; mt < 2; ++mt)
#pragma unroll
            for (int nt = 0; nt < 4; ++nt) acc[mt][nt] = f32x4{0.f, 0.f, 0.f, 0.f};

#pragma unroll
        for (int s = 0; s < 8; ++s) {
            if (s < 7)       STAGE_B(cb, s + 1, (s + 1) & 1);
            else if (cb < 7) STAGE_B(cb + 1, 0, 0);   // buf0: last read sealed at s=6
            if (s == 7 && cb == 7) { asm volatile("s_waitcnt vmcnt(0)" ::: "memory"); }
            else                   { asm volatile("s_waitcnt vmcnt(1)" ::: "memory"); }
            __builtin_amdgcn_s_barrier();
            COMPUTE(s, s & 1, acc);
            __builtin_amdgcn_s_barrier();
        }

        const int c0 = cb << 7;
        float wnv[4];
#pragma unroll
        for (int nt = 0; nt < 4; ++nt) wnv[nt] = wn[c0 + wn_ * 64 + nt * 16 + l15];
        const int ebase = ((cb << 1) | wn_) << 16;
#pragma unroll
        for (int mt = 0; mt < 2; ++mt) {
#pragma unroll
            for (int r = 0; r < 4; ++r) {
                // C/D layout: col = lane&15, row = (lane>>4)*4 + r
                float s0 = fmaf(-0.001953125f, acc[mt][0][r], wnv[0]);   // -2^-9 (w x1024)
                float s1 = fmaf(-0.001953125f, acc[mt][1][r], wnv[1]);
                float s2 = fmaf(-0.001953125f, acc[mt][2][r], wnv[2]);
                float s3 = fmaf(-0.001953125f, acc[mt][3][r], wnv[3]);
                float bv = fminf(fminf(s0, s1), fminf(s2, s3));
                DPP_MIN(0xB1)
                DPP_MIN(0x4E)
                DPP_MIN(0x141)
                DPP_MIN(0x140)
                float thr = bv + WWIN;
                u64 b0 = __ballot(s0 < thr), b1 = __ballot(s1 < thr);
                u64 b2 = __ballot(s2 < thr), b3 = __ballot(s3 < thr);
                int sh = 16 * l4;
                u64 msk = ((b0 >> sh) & 0xFFFFull)
                        | (((b1 >> sh) & 0xFFFFull) << 16)
                        | (((b2 >> sh) & 0xFFFFull) << 32)
                        | (((b3 >> sh) & 0xFFFFull) << 48);
                if (l15 == 0) {
                    int row = wm * 32 + mt * 16 + l4 * 4 + r;
                    btv[ebase + n0 + row] = bv;
                    bmk[ebase + n0 + row] = msk;
                }
            }
        }
    }
}

// ============ tail: finrescue core shared by fused / legacy variants ============
template <bool FUSE_GATHER>
__device__ __forceinline__ void finrescue_body(
        const float* __restrict__ z, const float* __restrict__ w,
        const float* __restrict__ s2, const float* __restrict__ btv,
        const u64* __restrict__ bmk, float* __restrict__ idxf_out,
        float* __restrict__ out0, float* __restrict__ out1,
        float (*zsh)[16][260], int (*codes)[16]) {
    const int t = threadIdx.x;
    const int lane = t & 63;
    const int wid = t >> 6;
    const int p = blockIdx.x;
    const int grp = (((p & 7) << 7) | (p >> 3)) * 4 + wid;
    const int n0 = grp * 16;
    const int r = lane >> 2;
    const int eq = lane & 3;
    const int n = n0 + r;

    float v0 = btv[((eq * 4 + 0) << 16) + n];
    float v1 = btv[((eq * 4 + 1) << 16) + n];
    float v2 = btv[((eq * 4 + 2) << 16) + n];
    float v3 = btv[((eq * 4 + 3) << 16) + n];
    float bv = 3.4e38f, b2 = 3.4e38f;
    int be = 0;
    {
        if (v0 < bv) { b2 = bv; bv = v0; be = eq * 4 + 0; } else b2 = fminf(b2, v0);
        if (v1 < bv) { b2 = bv; bv = v1; be = eq * 4 + 1; } else b2 = fminf(b2, v1);
        if (v2 < bv) { b2 = bv; bv = v2; be = eq * 4 + 2; } else b2 = fminf(b2, v2);
        if (v3 < bv) { b2 = bv; bv = v3; be = eq * 4 + 3; } else b2 = fminf(b2, v3);
    }
#pragma unroll
    for (int m = 1; m < 4; m <<= 1) {
        float ov = __shfl_xor(bv, m), o2 = __shfl_xor(b2, m);
        int oe = __shfl_xor(be, m);
        if (ov < bv || (ov == bv && oe < be)) { b2 = fminf(bv, o2); bv = ov; be = oe; }
        else b2 = fminf(b2, ov);
    }
    u64 wmask = bmk[((u64)be << 16) + n];
    int bi = be * 64 + (int)(__ffsll((long long)wmask) - 1);
    bool flag = (__popcll(wmask) > 1) || (b2 - bv < TAU);
    if (eq == 0) {
        idxf_out[n] = (float)bi;
        if (FUSE_GATHER) codes[wid][r] = bi;
    }

    u64 bal0 = __ballot(v0 <= bv + TAU);
    u64 bal1 = __ballot(v1 <= bv + TAU);
    u64 bal2 = __ballot(v2 <= bv + TAU);
    u64 bal3 = __ballot(v3 <= bv + TAU);

    u64 fb = __ballot(flag);
    if ((fb & 0x1111111111111111ull) != 0) {
        const float* zb = z + (size_t)(n0 >> 12) * 1048576 + (n0 & 4095);
#pragma unroll
        for (int it = 0; it < 16; ++it) {
            int d = it * 16 + (lane >> 2);
            float4 v = *reinterpret_cast<const float4*>(zb + (size_t)d * 4096 + (lane & 3) * 4);
            zsh[wid][(lane & 3) * 4 + 0][d] = v.x;
            zsh[wid][(lane & 3) * 4 + 1][d] = v.y;
            zsh[wid][(lane & 3) * 4 + 2][d] = v.z;
            zsh[wid][(lane & 3) * 4 + 3][d] = v.w;
        }
        asm volatile("s_waitcnt lgkmcnt(0)" ::: "memory");
        __builtin_amdgcn_sched_barrier(0);

#pragma unroll 1
        for (int r2 = 0; r2 < 16; ++r2) {
            if (!((fb >> (r2 * 4)) & 1)) continue;
            int nn = n0 + r2;
            int hh = (lane >> 3) & 1, jj = lane & 7;
            float w0 = zsh[wid][r2][hh * 128 + jj];
            float accj = __fmul_rn(w0, w0);
#pragma unroll
            for (int i = 1; i < 16; ++i) {
                float w2 = zsh[wid][r2][hh * 128 + i * 8 + jj];
                accj = __fadd_rn(accj, __fmul_rn(w2, w2));
            }
            float a1 = __fadd_rn(accj, __shfl_xor(accj, 1));
            float a2 = __fadd_rn(a1, __shfl_xor(a1, 2));
            float a4 = __fadd_rn(a2, __shfl_xor(a2, 4));
            float s1 = __fadd_rn(a4, __shfl_xor(a4, 8));

            float4 zr4 = *reinterpret_cast<const float4*>(&zsh[wid][r2][lane * 4]);
            float bv2 = 3.4e38f;
            int   bi2 = 0;
#pragma unroll
            for (int e = 0; e < 16; ++e) {
                u64 bal = (e & 3) == 0 ? bal0 : (e & 3) == 1 ? bal1 : (e & 3) == 2 ? bal2 : bal3;
                if ((bal >> (r2 * 4 + (e >> 2))) & 1) {
                    u64 m = bmk[((u64)e << 16) + nn];
                    while (m) {
                        int k = __ffsll((long long)m) - 1;
                        m &= m - 1;
                        int c = e * 64 + k;
                        const float* wp = w + (size_t)c * DDIM + lane * 4;
                        double md = 0.0;
                        md = fma((double)zr4.x, (double)wp[0], md);
                        md = fma((double)zr4.y, (double)wp[1], md);
                        md = fma((double)zr4.z, (double)wp[2], md);
                        md = fma((double)zr4.w, (double)wp[3], md);
#pragma unroll
                        for (int mm = 1; mm < 64; mm <<= 1) md += __shfl_xor(md, mm);
                        float dq = __fadd_rn((float)((double)s1 - 2.0 * md), s2[c]);
                        if (dq < bv2) { bv2 = dq; bi2 = c; }
                    }
                }
            }
            if (lane == 0) {
                idxf_out[nn] = (float)bi2;
                if (FUSE_GATHER) codes[wid][r2] = bi2;
            }
        }
    }

    if (FUSE_GATHER) {
        asm volatile("s_waitcnt lgkmcnt(0)" ::: "memory");
        __builtin_amdgcn_sched_barrier(0);
        int nr = lane & 15, c4 = lane >> 4;
        int code = codes[wid][nr];
        int nn = n0 + nr;
        size_t base = (size_t)(nn >> 12) * 1048576 + (nn & 4095);
#pragma unroll 4
        for (int p2 = 0; p2 < 16; ++p2) {
            int c = p2 * 16 + c4 * 4;
            float4 v = *reinterpret_cast<const float4*>(w + (size_t)code * DDIM + c);
            size_t o = base + (size_t)c * 4096;
            out0[o]         = v.x;
            out0[o + 4096]  = v.y;
            out0[o + 8192]  = v.z;
            out0[o + 12288] = v.w;
            out1[o]         = v.x;
            out1[o + 4096]  = v.y;
            out1[o + 8192]  = v.z;
            out1[o + 12288] = v.w;
        }
    }
}

__launch_bounds__(256, 2)
__global__ void finrescue_gather_k(const float* __restrict__ z, const float* __restrict__ w,
                                   const float* __restrict__ s2, const float* __restrict__ btv,
                                   const u64* __restrict__ bmk, float* __restrict__ idxf_out,
                                   float* __restrict__ out0, float* __restrict__ out1) {
    __shared__ float zsh[4][16][260];
    __shared__ int codes[4][16];
    finrescue_body<true>(z, w, s2, btv, bmk, idxf_out, out0, out1, zsh, codes);
}

__launch_bounds__(256, 2)
__global__ void finrescue_k(const float* __restrict__ z, const float* __restrict__ w,
                            const float* __restrict__ s2, const float* __restrict__ btv,
                            const u64* __restrict__ bmk, float* __restrict__ idxf_out) {
    __shared__ float zsh[4][16][260];
    finrescue_body<false>(z, w, s2, btv, bmk, idxf_out, nullptr, nullptr, zsh, nullptr);
}

// ---------------- legacy gather (fallback path) ----------------
__global__ void gather_k(const float* __restrict__ idxf, const float* __restrict__ w,
                         float* __restrict__ out0, float* __restrict__ out1) {
    int tid = blockIdx.x * 256 + threadIdx.x;
    int n   = tid & 65535;
    int c4  = tid >> 16;
    int code = (int)idxf[n];
    float4 v = *reinterpret_cast<const float4*>(w + (size_t)code * DDIM + c4 * 4);
    size_t off = (size_t)(n >> 12) * 1048576 + (size_t)c4 * 4 * 4096 + (n & 4095);
    out0[off]         = v.x;
    out0[off + 4096]  = v.y;
    out0[off + 8192]  = v.z;
    out0[off + 12288] = v.w;
    out1[off]         = v.x;
    out1[off + 4096]  = v.y;
    out1[off + 8192]  = v.z;
    out1[off + 12288] = v.w;
}

extern "C" void kernel_launch(void* const* d_in, const int* in_sizes, int n_in,
                              void* d_out, int out_size, void* d_ws, size_t ws_size,
                              hipStream_t stream) {
    const float* z = (const float*)d_in[0];
    const float* w = (const float*)d_in[1];
    float* out    = (float*)d_out;
    float* out0   = out;
    float* out1   = out + 16777216;
    float* outidx = out + 33554432;

    if (ws_size >= (size_t)14 * 1024 * 1024) {
        char* sb = (char*)d_ws;
        f16x8* w16 = (f16x8*)sb;                            // 512KB
        float* wn  = (float*)(sb + 1048576);                // 4KB
        float* btv = (float*)(sb + 2097152);                // 4MB  [16][65536]
        u64*   bmk = (u64*)(sb + 6291456);                  // 8MB  [16][65536]

        prep_w_k<<<132, 256, 0, stream>>>(w, w16, wn);
        argmin_fused_k<<<NROWS / 128, 512, 0, stream>>>(z, w16, wn, btv, bmk);
        finrescue_gather_k<<<NROWS / 64, 256, 0, stream>>>(z, w, wn, btv, bmk,
                                                           outidx, out0, out1);
    } else {
        char* s1b = (char*)out1;
        f16x8* w16 = (f16x8*)s1b;                           // 512KB
        float* wn  = (float*)(s1b + 1048576);               // 4KB
        float* btv = (float*)(s1b + 2097152);               // 4MB
        u64*   bmk = (u64*)(s1b + 10485760);                // 8MB

        prep_w_k<<<132, 256, 0, stream>>>(w, w16, wn);
        argmin_fused_k<<<NROWS / 128, 512, 0, stream>>>(z, w16, wn, btv, bmk);
        finrescue_k<<<NROWS / 64, 256, 0, stream>>>(z, w, wn, btv, bmk, outidx);
        gather_k<<<NROWS * 64 / 256, 256, 0, stream>>>(outidx, w, out0, out1);
    }
}